// Round 10
// baseline (483.898 us; speedup 1.0000x reference)
//
#include <hip/hip_runtime.h>
#include <hip/hip_bf16.h>
#include <stdint.h>

#define GEPS 1e-20f

typedef __bf16 bf16x8 __attribute__((ext_vector_type(8)));
typedef float  f32x4  __attribute__((ext_vector_type(4)));

typedef const __attribute__((address_space(1))) uint32_t* gptr32;
typedef __attribute__((address_space(3))) uint32_t* lptr32;

__device__ __forceinline__ void load_lds16(const void* g, void* l) {
    __builtin_amdgcn_global_load_lds((gptr32)g, (lptr32)l, 16, 0, 0);
}

__device__ __forceinline__ uint16_t f2bf(float v) {
    __hip_bfloat16 b = __float2bfloat16(v);
    return *(uint16_t*)&b;
}
__device__ __forceinline__ float bf2f(uint16_t b) {
    uint32_t u = (uint32_t)b << 16;
    return __builtin_bit_cast(float, u);
}

// hardware transcendentals: v_log_f32 = log2(x), v_exp_f32 = 2^x  (~1 ULP)
#define LN2   0.69314718056f
#define LOG2E 1.44269504089f
__device__ __forceinline__ float fast_log(float x) { return __builtin_amdgcn_logf(x) * LN2; }
__device__ __forceinline__ float fast_exp(float x) { return __builtin_amdgcn_exp2f(x * LOG2E); }
__device__ __forceinline__ float fast_exp2(float x) { return __builtin_amdgcn_exp2f(x); }
__device__ __forceinline__ float fast_rcp(float x)  { return __builtin_amdgcn_rcpf(x); }

__device__ __forceinline__ void store_val(uint16_t* C, size_t idx, float v) { C[idx] = f2bf(v); }
__device__ __forceinline__ void store_val(float* C, size_t idx, float v)    { C[idx] = v; }

// ---------------------------------------------------------------------------
// cast fp32 -> bf16, vectorized (n must be multiple of 4)
// ---------------------------------------------------------------------------
__global__ void cast_bf16(const float* __restrict__ in, uint16_t* __restrict__ out, int n) {
    int i = (blockIdx.x * blockDim.x + threadIdx.x) * 4;
    if (i < n) {
        float4 v = *(const float4*)(in + i);
        ushort4 o;
        o.x = f2bf(v.x); o.y = f2bf(v.y); o.z = f2bf(v.z); o.w = f2bf(v.w);
        *(ushort4*)(out + i) = o;
    }
}

// ---------------------------------------------------------------------------
// W (K x N, fp32, row-major) -> Wt (Npad x K, bf16, row-major), zero-pad n>=N
// ---------------------------------------------------------------------------
__global__ void transpose_cast(const float* __restrict__ W, uint16_t* __restrict__ Wt,
                               int K, int N, int Npad) {
    __shared__ float tile[64][65];
    const int k0 = blockIdx.y * 64, n0 = blockIdx.x * 64;
    const int tx = threadIdx.x & 63, ty = threadIdx.x >> 6;
    for (int r = ty; r < 64; r += 4) {
        int n = n0 + tx;
        tile[r][tx] = (n < N) ? W[(size_t)(k0 + r) * N + n] : 0.f;
    }
    __syncthreads();
    for (int r = ty; r < 64; r += 4) {
        Wt[(size_t)(n0 + r) * K + k0 + tx] = f2bf(tile[tx][r]);
    }
}

// ---------------------------------------------------------------------------
// 256x256 GEMM v4 — software-pipelined reads, 4-deep circular LDS.
// BK=32; 4 buffers x (A 16K + B 16K) = 128 KiB. 8 waves (2M x 4N), per-wave
// 128x64. Per K-tile: 2 phases x 16 MFMA (16x16x32), 1 barrier per phase.
// Verified on HW (rounds 8/9). NT=4 (K=128) degenerate case hand-verified:
// wrapped restages only touch buffers whose last reader drained >=1 barrier
// earlier, and rewrite identical tile data; dangling pre-reads drained.
// ---------------------------------------------------------------------------
#define BARRIER() asm volatile("s_barrier" ::: "memory")
#define VMW6()    asm volatile("s_waitcnt vmcnt(6)" ::: "memory")
#define VMW8()    asm volatile("s_waitcnt vmcnt(8)" ::: "memory")
#define DRAIN()   asm volatile("s_waitcnt vmcnt(0) lgkmcnt(0)" ::: "memory")
#define PRIO1()   __builtin_amdgcn_s_setprio(1)
#define PRIO0()   __builtin_amdgcn_s_setprio(0)

template<int ACT, typename OutT, bool SNG, int K>
__global__ __launch_bounds__(512, 2)
void gemm256(const uint16_t* __restrict__ A, const uint16_t* __restrict__ Bt,
             const float* __restrict__ bias, OutT* __restrict__ C,
             float* __restrict__ sngl, int Nout, int ldc) {
    constexpr int NT = K / 32;           // K-tiles of 32
    constexpr int NI = NT / 4;           // body covers 4 tiles
    constexpr int KB = K * 2;            // global row stride, bytes
    static_assert(NT >= 4 && (NT & (NT - 1)) == 0, "need pow2 >= 4 tiles");
    __shared__ __align__(16) char lds[131072];

    const int t = threadIdx.x;
    const int wave = t >> 6, lane = t & 63;
    const int quad = lane >> 4, r15 = lane & 15;
    const int wm = (wave >> 2) * 128, wn = (wave & 3) * 64;

    // ---- XCD-aware block remap (gridDim.y divisible by 8) ----
    const int nbx = gridDim.x;
    const int bid = blockIdx.y * nbx + blockIdx.x;
    const int xcd = bid & 7;
    const int sb  = bid >> 3;
    const int nidx = sb % nbx;
    const int midx = xcd * (gridDim.y >> 3) + sb / nbx;
    const int m0 = midx * 256, n0 = nidx * 256;

    // ---- staging addressing: thread t, load l covers LDS row l*128+(t>>2),
    //      chunk t&3; source chunk inverse-swizzled ----
    const int scb = ((t & 3) ^ ((t >> 3) & 3)) << 4;
    const char* Asrc = (const char*)A  + (size_t)(m0 + (t >> 2)) * KB + scb;
    const char* Bsrc = (const char*)Bt + (size_t)(n0 + (t >> 2)) * KB + scb;

    // ---- LDS read addressing (swizzled) ----
    const int cbR   = (quad ^ ((r15 >> 1) & 3)) << 4;
    const int aRowB = (wm + r15) * 64;
    const int bRowB = (wn + r15) * 64;

    f32x4 acc[8][4] = {};
    bf16x8 aLo[4], aHi[4], bE[4], bO[4];

    auto stgA = [&](int buf, int tile) {
        const char* s = Asrc + tile * 64;
        load_lds16(s,                    &lds[buf * 32768 + t * 16]);
        load_lds16(s + (size_t)128 * KB, &lds[buf * 32768 + 8192 + t * 16]);
    };
    auto stgB = [&](int buf, int tile) {
        const char* s = Bsrc + tile * 64;
        load_lds16(s,                    &lds[buf * 32768 + 16384 + t * 16]);
        load_lds16(s + (size_t)128 * KB, &lds[buf * 32768 + 24576 + t * 16]);
    };
    auto rdAlo = [&](int buf) {
        #pragma unroll
        for (int i = 0; i < 4; ++i)
            aLo[i] = *(const bf16x8*)&lds[buf * 32768 + aRowB + i * 1024 + cbR];
    };
    auto rdAhi = [&](int buf) {
        #pragma unroll
        for (int i = 0; i < 4; ++i)
            aHi[i] = *(const bf16x8*)&lds[buf * 32768 + aRowB + (4 + i) * 1024 + cbR];
    };
    auto rdB = [&](int buf, bf16x8 (&b)[4]) {
        #pragma unroll
        for (int i = 0; i < 4; ++i)
            b[i] = *(const bf16x8*)&lds[buf * 32768 + 16384 + bRowB + i * 1024 + cbR];
    };
    auto mfma16 = [&](int mlo, bf16x8 (&a)[4], bf16x8 (&b)[4]) {
        #pragma unroll
        for (int mi = 0; mi < 4; ++mi)
            #pragma unroll
            for (int ni = 0; ni < 4; ++ni)
                acc[mlo + mi][ni] = __builtin_amdgcn_mfma_f32_16x16x32_bf16(
                    a[mi], b[ni], acc[mlo + mi][ni], 0, 0, 0);
    };

    // ---- prologue: stage tiles 0,1,2 (12 loads); vmcnt(8) completes tile 0;
    //      pre-issue reads for phase (0,1) ----
    stgA(0, 0); stgB(0, 0);
    stgA(1, 1); stgB(1, 1);
    stgA(2, 2); stgB(2, 2);
    VMW8(); BARRIER();
    rdAlo(0); rdB(0, bE);

    #pragma unroll 1
    for (int ki = 0; ki < NI; ++ki) {
        const int T = ki * 4;
        // ---- tile T+0 (buf 0, b=E) ----
        rdAhi(0); stgA(3, (T + 3) & (NT - 1));
        PRIO1(); mfma16(0, aLo, bE); PRIO0();
        VMW6(); BARRIER();                       // publish tile T+1
        rdAlo(1); rdB(1, bO); stgB(3, (T + 3) & (NT - 1));
        PRIO1(); mfma16(4, aHi, bE); PRIO0();
        BARRIER();
        // ---- tile T+1 (buf 1, b=O) ----
        rdAhi(1); stgA(0, (T + 4) & (NT - 1));
        PRIO1(); mfma16(0, aLo, bO); PRIO0();
        VMW6(); BARRIER();                       // publish tile T+2
        rdAlo(2); rdB(2, bE); stgB(0, (T + 4) & (NT - 1));
        PRIO1(); mfma16(4, aHi, bO); PRIO0();
        BARRIER();
        // ---- tile T+2 (buf 2, b=E) ----
        rdAhi(2); stgA(1, (T + 5) & (NT - 1));
        PRIO1(); mfma16(0, aLo, bE); PRIO0();
        VMW6(); BARRIER();                       // publish tile T+3
        rdAlo(3); rdB(3, bO); stgB(1, (T + 5) & (NT - 1));
        PRIO1(); mfma16(4, aHi, bE); PRIO0();
        BARRIER();
        // ---- tile T+3 (buf 3, b=O) ----
        rdAhi(3); stgA(2, (T + 6) & (NT - 1));
        PRIO1(); mfma16(0, aLo, bO); PRIO0();
        VMW6(); BARRIER();                       // publish tile T+4
        rdAlo(0); rdB(0, bE); stgB(2, (T + 6) & (NT - 1));
        PRIO1(); mfma16(4, aHi, bO); PRIO0();
        BARRIER();
    }
    DRAIN();      // dangling stages + dangling pre-issued reads before LDS reuse
    BARRIER();

    // ---- epilogue: LDS-staged coalesced store (round-8 verified) ----
    // write: acc -> bf16 into swizzled [256][512B] tile (chunk XOR (row&7)<<4)
    #pragma unroll
    for (int ni = 0; ni < 4; ++ni) {
        const int col = wn + ni * 16 + r15;      // tile-local col
        const int gc  = n0 + col;                // global col
        const float bv = (gc < Nout) ? bias[gc] : 0.f;
        const bool is_sng = SNG && (gc == 31 || gc == 104 || gc == 928);
        #pragma unroll
        for (int mi = 0; mi < 8; ++mi) {
            #pragma unroll
            for (int r = 0; r < 4; ++r) {
                const int row = wm + mi * 16 + quad * 4 + r;   // tile-local row
                float v = acc[mi][ni][r] + bv;
                if (ACT == 1) v = (v > 0.f) ? v : (fast_exp(v) - 1.f);
                else if (ACT == 2) v = fast_rcp(1.f + fast_exp(-v));
                *(uint16_t*)&lds[row * 512 + ((col * 2) ^ ((row & 7) << 4))] = f2bf(v);
                if constexpr (SNG) {
                    if (is_sng) sngl[(size_t)(m0 + row) * 929 + gc] = v;
                }
            }
        }
    }
    asm volatile("s_waitcnt lgkmcnt(0)" ::: "memory");
    BARRIER();

    // read-back: 32 lanes cover one full 512B row -> 16B coalesced stores.
    {
        const int rt = t >> 5;          // 0..15: row-in-pass
        const int cc = t & 31;          // 0..31: 16B chunk in row
        #pragma unroll 1
        for (int pass = 0; pass < 16; ++pass) {
            const int row = pass * 16 + rt;
            f32x4 v4 = *(const f32x4*)&lds[row * 512 + ((cc * 16) ^ ((row & 7) << 4))];
            *(f32x4*)&C[(size_t)(m0 + row) * ldc + n0 + cc * 8] = v4;
        }
    }
}

// ---------------------------------------------------------------------------
// Gumbel-softmax epilogue v3: 4 rows per wave for ILP on the dependent
// log->fma->log chains and the shfl reduction chains (round-9: 79 us,
// VALUBusy 30%, HBM 37% -> latency-bound). seg_wide4 interleaves 4
// independent rows explicitly (all loops unrolled -> static reg indexing).
// lg stride 1024 (padded); u/out stride 929.
// ---------------------------------------------------------------------------
#define NEG_BIG (-1e30f)
#define Y2_LG   1.8033688011f   // 1.25 * log2(e)

__device__ __forceinline__ float y2_col(const uint16_t* __restrict__ rlg,
                                        const float* __restrict__ ru, int c) {
    float l2u   = __builtin_amdgcn_logf(ru[c] + GEPS);   // log2(u+eps)
    float inner = fmaf(-LN2, l2u, GEPS);                 // -ln(u+eps)+eps
    float l2i   = __builtin_amdgcn_logf(inner);          // log2(inner)
    return fmaf(Y2_LG, bf2f(rlg[c]), -1.25f * l2i);
}

template<int N, int OFF>
__device__ __forceinline__ void seg_small(const uint16_t* __restrict__ rlg,
                                          const float* __restrict__ ru,
                                          float* __restrict__ rout, int l32) {
    static_assert(N <= 32, "seg_small needs N<=32");
    constexpr int GS = (N <= 2) ? 2 : (N <= 4) ? 4 : (N <= 8) ? 8 : (N <= 16) ? 16 : 32;
    const bool act = l32 < N;
    const int  c   = OFF + l32;
    float y = act ? y2_col(rlg, ru, c) : NEG_BIG;
    float m = y;
    #pragma unroll
    for (int o = 1; o < GS; o <<= 1) m = fmaxf(m, __shfl_xor(m, o, 64));
    float e = act ? fast_exp2(y - m) : 0.f;
    float s = e;
    #pragma unroll
    for (int o = 1; o < GS; o <<= 1) s += __shfl_xor(s, o, 64);
    if (act) rout[c] = e * fast_rcp(s);
}

template<int N, int OFF>
__device__ __forceinline__ void seg_wide4(const uint16_t* __restrict__ lg0,
                                          const float* __restrict__ u0,
                                          float* __restrict__ o0, int lane) {
    constexpr int IT = (N + 63) / 64;
    float y[4][IT];
    float m[4] = {NEG_BIG, NEG_BIG, NEG_BIG, NEG_BIG};
    #pragma unroll
    for (int i = 0; i < IT; ++i) {
        const int j = i * 64 + lane;
        #pragma unroll
        for (int r = 0; r < 4; ++r) {
            y[r][i] = (j < N) ? y2_col(lg0 + (size_t)r * 1024, u0 + (size_t)r * 929, OFF + j)
                              : NEG_BIG;
            m[r] = fmaxf(m[r], y[r][i]);
        }
    }
    #pragma unroll
    for (int o = 1; o < 64; o <<= 1) {
        #pragma unroll
        for (int r = 0; r < 4; ++r) m[r] = fmaxf(m[r], __shfl_xor(m[r], o, 64));
    }
    float s[4] = {0.f, 0.f, 0.f, 0.f};
    #pragma unroll
    for (int i = 0; i < IT; ++i) {
        #pragma unroll
        for (int r = 0; r < 4; ++r) {
            float e = fast_exp2(y[r][i] - m[r]);   // inactive lanes: 2^(-1e30) = 0
            y[r][i] = e;
            s[r] += e;
        }
    }
    #pragma unroll
    for (int o = 1; o < 64; o <<= 1) {
        #pragma unroll
        for (int r = 0; r < 4; ++r) s[r] += __shfl_xor(s[r], o, 64);
    }
    float inv[4];
    #pragma unroll
    for (int r = 0; r < 4; ++r) inv[r] = fast_rcp(s[r]);
    #pragma unroll
    for (int i = 0; i < IT; ++i) {
        const int j = i * 64 + lane;
        if (j < N) {
            #pragma unroll
            for (int r = 0; r < 4; ++r)
                o0[(size_t)r * 929 + OFF + j] = y[r][i] * inv[r];
        }
    }
}

__global__ __launch_bounds__(256)
void gumbel_epilogue(const uint16_t* __restrict__ lg, float* __restrict__ out,
                     const float* __restrict__ u, int B) {
    const int wave = threadIdx.x >> 6, lane = threadIdx.x & 63;
    const int l32  = lane & 31, half = lane >> 5;
    const int r0 = blockIdx.x * 16 + wave * 4;   // 4 rows per wave
    if (r0 >= B) return;

    // small segments: each 32-lane half owns 2 rows, processed sequentially
    #pragma unroll
    for (int rr = 0; rr < 2; ++rr) {
        const int row = r0 + half * 2 + rr;
        const uint16_t* lgH = lg  + (size_t)row * 1024;
        const float*    uH  = u   + (size_t)row * 929;
        float*          oH  = out + (size_t)row * 929;
        seg_small<29,   0>(lgH, uH, oH, l32);
        seg_small< 2,  29>(lgH, uH, oH, l32);
        seg_small< 6,  32>(lgH, uH, oH, l32);
        seg_small< 7,  38>(lgH, uH, oH, l32);
        seg_small<24, 105>(lgH, uH, oH, l32);
        seg_small< 3, 916>(lgH, uH, oH, l32);
        seg_small< 9, 919>(lgH, uH, oH, l32);
    }

    // wide segments: 4 rows explicitly interleaved (4x ILP on shfl chains)
    const uint16_t* lg0 = lg  + (size_t)r0 * 1024;
    const float*    u0  = u   + (size_t)r0 * 929;
    float*          o0  = out + (size_t)r0 * 929;
    seg_wide4< 59,  45>(lg0, u0, o0, lane);
    seg_wide4< 76, 129>(lg0, u0, o0, lane);
    seg_wide4<711, 205>(lg0, u0, o0, lane);
}

// ---------------------------------------------------------------------------
extern "C" void kernel_launch(void* const* d_in, const int* in_sizes, int n_in,
                              void* d_out, int out_size, void* d_ws, size_t ws_size,
                              hipStream_t stream) {
    const float* x  = (const float*)d_in[0];
    const float* W1 = (const float*)d_in[1];
    const float* b1 = (const float*)d_in[2];
    const float* W2 = (const float*)d_in[3];
    const float* b2 = (const float*)d_in[4];
    const float* W3 = (const float*)d_in[5];
    const float* b3 = (const float*)d_in[6];
    const float* u  = (const float*)d_in[7];
    float* out = (float*)d_out;

    const int B = 32768, D = 128, H = 1024, O = 929, OP = 1024;

    char* ws = (char*)d_ws;
    uint16_t* xb  = (uint16_t*)ws; ws += (size_t)B * D * 2;   // 8 MB
    uint16_t* w1t = (uint16_t*)ws; ws += (size_t)H * D * 2;   // 0.25 MB
    uint16_t* w2t = (uint16_t*)ws; ws += (size_t)H * H * 2;   // 2 MB
    uint16_t* w3t = (uint16_t*)ws; ws += (size_t)OP * H * 2;  // 2 MB
    uint16_t* h1  = (uint16_t*)ws; ws += (size_t)B * H * 2;   // 64 MB
    uint16_t* h2  = (uint16_t*)ws; ws += (size_t)B * H * 2;   // 64 MB
    // logits (bf16, B x 1024 padded = 64 MB) alias h1 — h1 dead after GEMM2
    uint16_t* lg  = h1;

    cast_bf16<<<(B * D / 4 + 255) / 256, 256, 0, stream>>>(x, xb, B * D);
    transpose_cast<<<dim3(H / 64, D / 64), 256, 0, stream>>>(W1, w1t, D, H, H);
    transpose_cast<<<dim3(H / 64, H / 64), 256, 0, stream>>>(W2, w2t, H, H, H);
    transpose_cast<<<dim3(OP / 64, H / 64), 256, 0, stream>>>(W3, w3t, H, O, OP);

    // h1 = elu(x @ W1 + b1)   — now on the pipelined 256^2 kernel (K=128,
    // NT=4 degenerate case): coalesced epilogue kills the ~2.5x write
    // amplification that kept the old gemm_bt at ~75 us.
    gemm256<1, uint16_t, false, 128><<<dim3(H / 256, B / 256), 512, 0, stream>>>(
        xb, w1t, b1, h1, nullptr, H, H);
    // h2 = sigmoid(h1 @ W2 + b2)
    gemm256<2, uint16_t, false, 1024><<<dim3(H / 256, B / 256), 512, 0, stream>>>(
        h1, w2t, b2, h2, nullptr, H, H);
    // logits -> padded bf16 buffer (ldc=1024); fp32 singletons -> d_out
    gemm256<0, uint16_t, true, 1024><<<dim3(OP / 256, B / 256), 512, 0, stream>>>(
        h2, w3t, b3, lg, out, O, 1024);

    // gumbel softmax: bf16 logits (stride 1024) -> fp32 out (stride 929)
    gumbel_epilogue<<<B / 16, 256, 0, stream>>>(lg, out, u, B);
}

// Round 12
// 460.199 us; speedup vs baseline: 1.0515x; 1.0515x over previous
//
#include <hip/hip_runtime.h>
#include <hip/hip_bf16.h>
#include <stdint.h>

#define GEPS 1e-20f

typedef __bf16 bf16x8 __attribute__((ext_vector_type(8)));
typedef float  f32x4  __attribute__((ext_vector_type(4)));

typedef const __attribute__((address_space(1))) uint32_t* gptr32;
typedef __attribute__((address_space(3))) uint32_t* lptr32;

__device__ __forceinline__ void load_lds16(const void* g, void* l) {
    __builtin_amdgcn_global_load_lds((gptr32)g, (lptr32)l, 16, 0, 0);
}

__device__ __forceinline__ uint16_t f2bf(float v) {
    __hip_bfloat16 b = __float2bfloat16(v);
    return *(uint16_t*)&b;
}
__device__ __forceinline__ float bf2f(uint16_t b) {
    uint32_t u = (uint32_t)b << 16;
    return __builtin_bit_cast(float, u);
}

// hardware transcendentals: v_log_f32 = log2(x), v_exp_f32 = 2^x  (~1 ULP)
#define LN2   0.69314718056f
#define LOG2E 1.44269504089f
__device__ __forceinline__ float fast_log(float x) { return __builtin_amdgcn_logf(x) * LN2; }
__device__ __forceinline__ float fast_exp(float x) { return __builtin_amdgcn_exp2f(x * LOG2E); }
__device__ __forceinline__ float fast_exp2(float x) { return __builtin_amdgcn_exp2f(x); }
__device__ __forceinline__ float fast_rcp(float x)  { return __builtin_amdgcn_rcpf(x); }

__device__ __forceinline__ void store_val(uint16_t* C, size_t idx, float v) { C[idx] = f2bf(v); }
__device__ __forceinline__ void store_val(float* C, size_t idx, float v)    { C[idx] = v; }

// ---------------------------------------------------------------------------
// cast fp32 -> bf16, vectorized (n must be multiple of 4)
// ---------------------------------------------------------------------------
__global__ void cast_bf16(const float* __restrict__ in, uint16_t* __restrict__ out, int n) {
    int i = (blockIdx.x * blockDim.x + threadIdx.x) * 4;
    if (i < n) {
        float4 v = *(const float4*)(in + i);
        ushort4 o;
        o.x = f2bf(v.x); o.y = f2bf(v.y); o.z = f2bf(v.z); o.w = f2bf(v.w);
        *(ushort4*)(out + i) = o;
    }
}

// ---------------------------------------------------------------------------
// W (K x N, fp32, row-major) -> Wt (Npad x K, bf16, row-major), zero-pad n>=N
// ---------------------------------------------------------------------------
__global__ void transpose_cast(const float* __restrict__ W, uint16_t* __restrict__ Wt,
                               int K, int N, int Npad) {
    __shared__ float tile[64][65];
    const int k0 = blockIdx.y * 64, n0 = blockIdx.x * 64;
    const int tx = threadIdx.x & 63, ty = threadIdx.x >> 6;
    for (int r = ty; r < 64; r += 4) {
        int n = n0 + tx;
        tile[r][tx] = (n < N) ? W[(size_t)(k0 + r) * N + n] : 0.f;
    }
    __syncthreads();
    for (int r = ty; r < 64; r += 4) {
        Wt[(size_t)(n0 + r) * K + k0 + tx] = f2bf(tile[tx][r]);
    }
}

// ---------------------------------------------------------------------------
// 256x256 GEMM v4 — software-pipelined reads, 4-deep circular LDS.
// BK=32; 4 buffers x (A 16K + B 16K) = 128 KiB. 8 waves (2M x 4N), per-wave
// 128x64. Per K-tile: 2 phases x 16 MFMA (16x16x32), 1 barrier per phase.
// Verified on HW (rounds 8/9/10), incl. the NT=4 (K=128) degenerate case.
// ---------------------------------------------------------------------------
#define BARRIER() asm volatile("s_barrier" ::: "memory")
#define VMW6()    asm volatile("s_waitcnt vmcnt(6)" ::: "memory")
#define VMW8()    asm volatile("s_waitcnt vmcnt(8)" ::: "memory")
#define DRAIN()   asm volatile("s_waitcnt vmcnt(0) lgkmcnt(0)" ::: "memory")
#define PRIO1()   __builtin_amdgcn_s_setprio(1)
#define PRIO0()   __builtin_amdgcn_s_setprio(0)

template<int ACT, typename OutT, bool SNG, int K>
__global__ __launch_bounds__(512, 2)
void gemm256(const uint16_t* __restrict__ A, const uint16_t* __restrict__ Bt,
             const float* __restrict__ bias, OutT* __restrict__ C,
             float* __restrict__ sngl, int Nout, int ldc) {
    constexpr int NT = K / 32;           // K-tiles of 32
    constexpr int NI = NT / 4;           // body covers 4 tiles
    constexpr int KB = K * 2;            // global row stride, bytes
    static_assert(NT >= 4 && (NT & (NT - 1)) == 0, "need pow2 >= 4 tiles");
    __shared__ __align__(16) char lds[131072];

    const int t = threadIdx.x;
    const int wave = t >> 6, lane = t & 63;
    const int quad = lane >> 4, r15 = lane & 15;
    const int wm = (wave >> 2) * 128, wn = (wave & 3) * 64;

    // ---- XCD-aware block remap (gridDim.y divisible by 8) ----
    const int nbx = gridDim.x;
    const int bid = blockIdx.y * nbx + blockIdx.x;
    const int xcd = bid & 7;
    const int sb  = bid >> 3;
    const int nidx = sb % nbx;
    const int midx = xcd * (gridDim.y >> 3) + sb / nbx;
    const int m0 = midx * 256, n0 = nidx * 256;

    // ---- staging addressing: thread t, load l covers LDS row l*128+(t>>2),
    //      chunk t&3; source chunk inverse-swizzled ----
    const int scb = ((t & 3) ^ ((t >> 3) & 3)) << 4;
    const char* Asrc = (const char*)A  + (size_t)(m0 + (t >> 2)) * KB + scb;
    const char* Bsrc = (const char*)Bt + (size_t)(n0 + (t >> 2)) * KB + scb;

    // ---- LDS read addressing (swizzled) ----
    const int cbR   = (quad ^ ((r15 >> 1) & 3)) << 4;
    const int aRowB = (wm + r15) * 64;
    const int bRowB = (wn + r15) * 64;

    f32x4 acc[8][4] = {};
    bf16x8 aLo[4], aHi[4], bE[4], bO[4];

    auto stgA = [&](int buf, int tile) {
        const char* s = Asrc + tile * 64;
        load_lds16(s,                    &lds[buf * 32768 + t * 16]);
        load_lds16(s + (size_t)128 * KB, &lds[buf * 32768 + 8192 + t * 16]);
    };
    auto stgB = [&](int buf, int tile) {
        const char* s = Bsrc + tile * 64;
        load_lds16(s,                    &lds[buf * 32768 + 16384 + t * 16]);
        load_lds16(s + (size_t)128 * KB, &lds[buf * 32768 + 24576 + t * 16]);
    };
    auto rdAlo = [&](int buf) {
        #pragma unroll
        for (int i = 0; i < 4; ++i)
            aLo[i] = *(const bf16x8*)&lds[buf * 32768 + aRowB + i * 1024 + cbR];
    };
    auto rdAhi = [&](int buf) {
        #pragma unroll
        for (int i = 0; i < 4; ++i)
            aHi[i] = *(const bf16x8*)&lds[buf * 32768 + aRowB + (4 + i) * 1024 + cbR];
    };
    auto rdB = [&](int buf, bf16x8 (&b)[4]) {
        #pragma unroll
        for (int i = 0; i < 4; ++i)
            b[i] = *(const bf16x8*)&lds[buf * 32768 + 16384 + bRowB + i * 1024 + cbR];
    };
    auto mfma16 = [&](int mlo, bf16x8 (&a)[4], bf16x8 (&b)[4]) {
        #pragma unroll
        for (int mi = 0; mi < 4; ++mi)
            #pragma unroll
            for (int ni = 0; ni < 4; ++ni)
                acc[mlo + mi][ni] = __builtin_amdgcn_mfma_f32_16x16x32_bf16(
                    a[mi], b[ni], acc[mlo + mi][ni], 0, 0, 0);
    };

    // ---- prologue: stage tiles 0,1,2 (12 loads); vmcnt(8) completes tile 0;
    //      pre-issue reads for phase (0,1) ----
    stgA(0, 0); stgB(0, 0);
    stgA(1, 1); stgB(1, 1);
    stgA(2, 2); stgB(2, 2);
    VMW8(); BARRIER();
    rdAlo(0); rdB(0, bE);

    #pragma unroll 1
    for (int ki = 0; ki < NI; ++ki) {
        const int T = ki * 4;
        // ---- tile T+0 (buf 0, b=E) ----
        rdAhi(0); stgA(3, (T + 3) & (NT - 1));
        PRIO1(); mfma16(0, aLo, bE); PRIO0();
        VMW6(); BARRIER();                       // publish tile T+1
        rdAlo(1); rdB(1, bO); stgB(3, (T + 3) & (NT - 1));
        PRIO1(); mfma16(4, aHi, bE); PRIO0();
        BARRIER();
        // ---- tile T+1 (buf 1, b=O) ----
        rdAhi(1); stgA(0, (T + 4) & (NT - 1));
        PRIO1(); mfma16(0, aLo, bO); PRIO0();
        VMW6(); BARRIER();                       // publish tile T+2
        rdAlo(2); rdB(2, bE); stgB(0, (T + 4) & (NT - 1));
        PRIO1(); mfma16(4, aHi, bO); PRIO0();
        BARRIER();
        // ---- tile T+2 (buf 2, b=E) ----
        rdAhi(2); stgA(1, (T + 5) & (NT - 1));
        PRIO1(); mfma16(0, aLo, bE); PRIO0();
        VMW6(); BARRIER();                       // publish tile T+3
        rdAlo(3); rdB(3, bO); stgB(1, (T + 5) & (NT - 1));
        PRIO1(); mfma16(4, aHi, bE); PRIO0();
        BARRIER();
        // ---- tile T+3 (buf 3, b=O) ----
        rdAhi(3); stgA(2, (T + 6) & (NT - 1));
        PRIO1(); mfma16(0, aLo, bO); PRIO0();
        VMW6(); BARRIER();                       // publish tile T+4
        rdAlo(0); rdB(0, bE); stgB(2, (T + 6) & (NT - 1));
        PRIO1(); mfma16(4, aHi, bO); PRIO0();
        BARRIER();
    }
    DRAIN();      // dangling stages + dangling pre-issued reads before LDS reuse
    BARRIER();

    // ---- epilogue: LDS-staged coalesced store (round-8 verified) ----
    // write: acc -> bf16 into swizzled [256][512B] tile (chunk XOR (row&7)<<4)
    #pragma unroll
    for (int ni = 0; ni < 4; ++ni) {
        const int col = wn + ni * 16 + r15;      // tile-local col
        const int gc  = n0 + col;                // global col
        const float bv = (gc < Nout) ? bias[gc] : 0.f;
        const bool is_sng = SNG && (gc == 31 || gc == 104 || gc == 928);
        #pragma unroll
        for (int mi = 0; mi < 8; ++mi) {
            #pragma unroll
            for (int r = 0; r < 4; ++r) {
                const int row = wm + mi * 16 + quad * 4 + r;   // tile-local row
                float v = acc[mi][ni][r] + bv;
                if (ACT == 1) v = (v > 0.f) ? v : (fast_exp(v) - 1.f);
                else if (ACT == 2) v = fast_rcp(1.f + fast_exp(-v));
                *(uint16_t*)&lds[row * 512 + ((col * 2) ^ ((row & 7) << 4))] = f2bf(v);
                if constexpr (SNG) {
                    if (is_sng) sngl[(size_t)(m0 + row) * 929 + gc] = v;
                }
            }
        }
    }
    asm volatile("s_waitcnt lgkmcnt(0)" ::: "memory");
    BARRIER();

    // read-back: 32 lanes cover one full 512B row -> 16B coalesced stores.
    {
        const int rt = t >> 5;          // 0..15: row-in-pass
        const int cc = t & 31;          // 0..31: 16B chunk in row
        #pragma unroll 1
        for (int pass = 0; pass < 16; ++pass) {
            const int row = pass * 16 + rt;
            f32x4 v4 = *(const f32x4*)&lds[row * 512 + ((cc * 16) ^ ((row & 7) << 4))];
            *(f32x4*)&C[(size_t)(m0 + row) * ldc + n0 + cc * 8] = v4;
        }
    }
}

// ---------------------------------------------------------------------------
// Gumbel-softmax epilogue v2 (round-9 verified operating point: ~79 us,
// VGPR 28, occupancy ~68%): no LDS, register-resident y, 2 rows per wave.
//   y2 = 1.8033688*logit - 1.25*log2(-ln2*log2(u+eps) + eps)
//   p  = 2^(y2 - max) / sum(2^(y2 - max))
// Round-10 lesson: 4-row ILP variant halves occupancy (VGPR 56) and
// REGRESSES ~21 us — this kernel is TLP/latency-bound, keep state small.
// lg stride 1024 (padded); u/out stride 929.
// ---------------------------------------------------------------------------
#define NEG_BIG (-1e30f)
#define Y2_LG   1.8033688011f   // 1.25 * log2(e)

__device__ __forceinline__ float y2_col(const uint16_t* __restrict__ rlg,
                                        const float* __restrict__ ru, int c) {
    float l2u   = __builtin_amdgcn_logf(ru[c] + GEPS);   // log2(u+eps)
    float inner = fmaf(-LN2, l2u, GEPS);                 // -ln(u+eps)+eps
    float l2i   = __builtin_amdgcn_logf(inner);          // log2(inner)
    return fmaf(Y2_LG, bf2f(rlg[c]), -1.25f * l2i);
}

template<int N, int OFF>
__device__ __forceinline__ void seg_small(const uint16_t* __restrict__ rlg,
                                          const float* __restrict__ ru,
                                          float* __restrict__ rout, int l32) {
    static_assert(N <= 32, "seg_small needs N<=32");
    constexpr int GS = (N <= 2) ? 2 : (N <= 4) ? 4 : (N <= 8) ? 8 : (N <= 16) ? 16 : 32;
    const bool act = l32 < N;
    const int  c   = OFF + l32;
    float y = act ? y2_col(rlg, ru, c) : NEG_BIG;
    float m = y;
    #pragma unroll
    for (int o = 1; o < GS; o <<= 1) m = fmaxf(m, __shfl_xor(m, o, 64));
    float e = act ? fast_exp2(y - m) : 0.f;
    float s = e;
    #pragma unroll
    for (int o = 1; o < GS; o <<= 1) s += __shfl_xor(s, o, 64);
    if (act) rout[c] = e * fast_rcp(s);
}

template<int N, int OFF>
__device__ __forceinline__ void seg_wide(const uint16_t* __restrict__ rlg,
                                         const float* __restrict__ ru,
                                         float* __restrict__ rout, int lane) {
    constexpr int IT = (N + 63) / 64;
    float y[IT];
    float m = NEG_BIG;
    #pragma unroll
    for (int i = 0; i < IT; ++i) {
        const int j = i * 64 + lane;
        y[i] = (j < N) ? y2_col(rlg, ru, OFF + j) : NEG_BIG;
        m = fmaxf(m, y[i]);
    }
    #pragma unroll
    for (int o = 1; o < 64; o <<= 1) m = fmaxf(m, __shfl_xor(m, o, 64));
    float s = 0.f;
    #pragma unroll
    for (int i = 0; i < IT; ++i) {
        float e = fast_exp2(y[i] - m);   // inactive lanes: 2^(-1e30) = 0
        y[i] = e;
        s += e;
    }
    #pragma unroll
    for (int o = 1; o < 64; o <<= 1) s += __shfl_xor(s, o, 64);
    const float inv = fast_rcp(s);
    #pragma unroll
    for (int i = 0; i < IT; ++i) {
        const int j = i * 64 + lane;
        if (j < N) rout[OFF + j] = y[i] * inv;
    }
}

__global__ __launch_bounds__(256)
void gumbel_epilogue(const uint16_t* __restrict__ lg, float* __restrict__ out,
                     const float* __restrict__ u, int B) {
    const int wave = threadIdx.x >> 6, lane = threadIdx.x & 63;
    const int l32  = lane & 31, half = lane >> 5;
    const int rowA = blockIdx.x * 8 + wave * 2;
    if (rowA >= B) return;

    const size_t uoA  = (size_t)rowA * 929;        // u / out stride 929
    const size_t uoB  = uoA + 929;
    const size_t lgoA = (size_t)rowA * 1024;       // lg stride 1024 (padded)
    const size_t lgoB = lgoA + 1024;
    const size_t uoH  = half ? uoB  : uoA;
    const size_t lgoH = half ? lgoB : lgoA;

    // paired small segments: each 32-lane half handles its own row
    const uint16_t* lgH = lg  + lgoH;
    const float*    uH  = u   + uoH;
    float*          oH  = out + uoH;
    seg_small<29,   0>(lgH, uH, oH, l32);
    seg_small< 2,  29>(lgH, uH, oH, l32);
    seg_small< 6,  32>(lgH, uH, oH, l32);
    seg_small< 7,  38>(lgH, uH, oH, l32);
    seg_small<24, 105>(lgH, uH, oH, l32);
    seg_small< 3, 916>(lgH, uH, oH, l32);
    seg_small< 9, 919>(lgH, uH, oH, l32);

    // wide segments: full wave, one row at a time (independent -> ILP)
    const uint16_t* lgA = lg + lgoA; const float* uA = u + uoA; float* oA = out + uoA;
    const uint16_t* lgB = lg + lgoB; const float* uB = u + uoB; float* oB = out + uoB;
    seg_wide< 59,  45>(lgA, uA, oA, lane);
    seg_wide< 59,  45>(lgB, uB, oB, lane);
    seg_wide< 76, 129>(lgA, uA, oA, lane);
    seg_wide< 76, 129>(lgB, uB, oB, lane);
    seg_wide<711, 205>(lgA, uA, oA, lane);
    seg_wide<711, 205>(lgB, uB, oB, lane);
}

// ---------------------------------------------------------------------------
extern "C" void kernel_launch(void* const* d_in, const int* in_sizes, int n_in,
                              void* d_out, int out_size, void* d_ws, size_t ws_size,
                              hipStream_t stream) {
    const float* x  = (const float*)d_in[0];
    const float* W1 = (const float*)d_in[1];
    const float* b1 = (const float*)d_in[2];
    const float* W2 = (const float*)d_in[3];
    const float* b2 = (const float*)d_in[4];
    const float* W3 = (const float*)d_in[5];
    const float* b3 = (const float*)d_in[6];
    const float* u  = (const float*)d_in[7];
    float* out = (float*)d_out;

    const int B = 32768, D = 128, H = 1024, O = 929, OP = 1024;

    char* ws = (char*)d_ws;
    uint16_t* xb  = (uint16_t*)ws; ws += (size_t)B * D * 2;   // 8 MB
    uint16_t* w1t = (uint16_t*)ws; ws += (size_t)H * D * 2;   // 0.25 MB
    uint16_t* w2t = (uint16_t*)ws; ws += (size_t)H * H * 2;   // 2 MB
    uint16_t* w3t = (uint16_t*)ws; ws += (size_t)OP * H * 2;  // 2 MB
    uint16_t* h1  = (uint16_t*)ws; ws += (size_t)B * H * 2;   // 64 MB
    uint16_t* h2  = (uint16_t*)ws; ws += (size_t)B * H * 2;   // 64 MB
    // logits (bf16, B x 1024 padded = 64 MB) alias h1 — h1 dead after GEMM2
    uint16_t* lg  = h1;

    cast_bf16<<<(B * D / 4 + 255) / 256, 256, 0, stream>>>(x, xb, B * D);
    transpose_cast<<<dim3(H / 64, D / 64), 256, 0, stream>>>(W1, w1t, D, H, H);
    transpose_cast<<<dim3(H / 64, H / 64), 256, 0, stream>>>(W2, w2t, H, H, H);
    transpose_cast<<<dim3(OP / 64, H / 64), 256, 0, stream>>>(W3, w3t, H, O, OP);

    // h1 = elu(x @ W1 + b1)   (K=128 on the pipelined 256^2 kernel)
    gemm256<1, uint16_t, false, 128><<<dim3(H / 256, B / 256), 512, 0, stream>>>(
        xb, w1t, b1, h1, nullptr, H, H);
    // h2 = sigmoid(h1 @ W2 + b2)
    gemm256<2, uint16_t, false, 1024><<<dim3(H / 256, B / 256), 512, 0, stream>>>(
        h1, w2t, b2, h2, nullptr, H, H);
    // logits -> padded bf16 buffer (ldc=1024); fp32 singletons -> d_out
    gemm256<0, uint16_t, true, 1024><<<dim3(OP / 256, B / 256), 512, 0, stream>>>(
        h2, w3t, b3, lg, out, O, 1024);

    // gumbel softmax: bf16 logits (stride 1024) -> fp32 out (stride 929)
    gumbel_epilogue<<<B / 8, 256, 0, stream>>>(lg, out, u, B);
}